// Round 4
// baseline (5006.902 us; speedup 1.0000x reference)
//
#include <hip/hip_runtime.h>
#include <math.h>

// Problem constants
#define NB   4        // batch
#define NH   16       // heads
#define DHD  64       // head dim
#define SL   2048     // Lq == Lk
#define DM   1024     // model dim
#define TOPK 205      // ceil(2048 * 0.1)

// ws layout (floats):
//  Q head-major [B,H,L,DH]  : 8M   @ 0
//  K head-major             : 8M   @ 8M
//  V head-major (tanh)      : 8M   @ 16M
//  CTX [B,L,D]              : 8M   @ 24M
//  S scores [chunk,L,L]     : adaptive @ 32M
//  stats [chunk*2048] float4: after S
#define WS_Q   0
#define WS_K   8388608
#define WS_V   16777216
#define WS_CTX 25165824
#define WS_S   33554432
#define S_PER_BH     4194304   // 2048*2048 floats per (b,h) plane
#define STATS_PER_BH 8192      // 2048 rows * 4 floats

// ---------------------------------------------------------------------------
// Projection GEMM: out = X @ W^T + bias.  X [8192,1024], W [1024,1024].
// mode 0: head-major write; 1: +tanh; 2: plain [M,N].
// 128x128 tile, BK=16, 256 threads, 8x8 per thread (2x2 quads of float4).
// ---------------------------------------------------------------------------
__global__ __launch_bounds__(256) void gemm_proj(const float* __restrict__ X,
                                                 const float* __restrict__ W,
                                                 const float* __restrict__ bias,
                                                 float* __restrict__ out,
                                                 int mode)
{
    __shared__ __align__(16) float Xs[16][132];
    __shared__ __align__(16) float Ws[16][132];
    const int t  = threadIdx.x;
    const int tx = t & 15, ty = t >> 4;
    const int n0 = blockIdx.x * 128;
    const int m0 = blockIdx.y * 128;
    const int lr = t >> 1;          // 0..127
    const int lk = (t & 1) * 8;     // 0 or 8

    float c[8][8] = {};

    const float* Xp = &X[(size_t)(m0 + lr) * DM + lk];
    const float* Wp = &W[(size_t)(n0 + lr) * DM + lk];

    for (int k0 = 0; k0 < DM; k0 += 16) {
        float4 xa0 = *(const float4*)(Xp + k0);
        float4 xa1 = *(const float4*)(Xp + k0 + 4);
        float4 wa0 = *(const float4*)(Wp + k0);
        float4 wa1 = *(const float4*)(Wp + k0 + 4);
        __syncthreads();
        Xs[lk+0][lr]=xa0.x; Xs[lk+1][lr]=xa0.y; Xs[lk+2][lr]=xa0.z; Xs[lk+3][lr]=xa0.w;
        Xs[lk+4][lr]=xa1.x; Xs[lk+5][lr]=xa1.y; Xs[lk+6][lr]=xa1.z; Xs[lk+7][lr]=xa1.w;
        Ws[lk+0][lr]=wa0.x; Ws[lk+1][lr]=wa0.y; Ws[lk+2][lr]=wa0.z; Ws[lk+3][lr]=wa0.w;
        Ws[lk+4][lr]=wa1.x; Ws[lk+5][lr]=wa1.y; Ws[lk+6][lr]=wa1.z; Ws[lk+7][lr]=wa1.w;
        __syncthreads();
        #pragma unroll
        for (int kk = 0; kk < 16; ++kk) {
            float4 a0 = *(const float4*)&Xs[kk][ty * 4];
            float4 a1 = *(const float4*)&Xs[kk][ty * 4 + 64];
            float4 b0 = *(const float4*)&Ws[kk][tx * 4];
            float4 b1 = *(const float4*)&Ws[kk][tx * 4 + 64];
            float a_[8] = {a0.x,a0.y,a0.z,a0.w,a1.x,a1.y,a1.z,a1.w};
            float b_[8] = {b0.x,b0.y,b0.z,b0.w,b1.x,b1.y,b1.z,b1.w};
            #pragma unroll
            for (int i = 0; i < 8; ++i)
                #pragma unroll
                for (int j = 0; j < 8; ++j)
                    c[i][j] = fmaf(a_[i], b_[j], c[i][j]);
        }
    }

    float4 bi0 = *(const float4*)&bias[n0 + tx * 4];
    float4 bi1 = *(const float4*)&bias[n0 + tx * 4 + 64];
    float bb[8] = {bi0.x,bi0.y,bi0.z,bi0.w,bi1.x,bi1.y,bi1.z,bi1.w};
    #pragma unroll
    for (int i = 0; i < 8; ++i) {
        int rr = (i < 4) ? (ty * 4 + i) : (64 + ty * 4 + (i - 4));
        int m  = m0 + rr;
        float r0[4], r1[4];
        #pragma unroll
        for (int j = 0; j < 4; ++j) {
            float v0 = c[i][j]     + bb[j];
            float v1 = c[i][j + 4] + bb[j + 4];
            if (mode == 1) { v0 = tanhf(v0); v1 = tanhf(v1); }
            r0[j] = v0; r1[j] = v1;
        }
        float4 w0 = make_float4(r0[0], r0[1], r0[2], r0[3]);
        float4 w1 = make_float4(r1[0], r1[1], r1[2], r1[3]);
        if (mode == 2) {
            *(float4*)&out[(size_t)m * DM + n0 + tx * 4]      = w0;
            *(float4*)&out[(size_t)m * DM + n0 + 64 + tx * 4] = w1;
        } else {
            int b = m >> 11, l = m & 2047;
            int h0 = n0 >> 6;
            *(float4*)&out[(((size_t)(b * NH + h0    )) * SL + l) * DHD + tx * 4] = w0;
            *(float4*)&out[(((size_t)(b * NH + h0 + 1)) * SL + l) * DHD + tx * 4] = w1;
        }
    }
}

// ---------------------------------------------------------------------------
// Scores: S[z,q,k] = 0.25 * sum_d Q[bh,q,d]*K[bh,k,d]; masked -> -20000
// 128x128 tile, BK=16 over K=64. grid (ktile=16, qtile=16, chunk).
// ---------------------------------------------------------------------------
__global__ __launch_bounds__(256) void scores_kernel(const float* __restrict__ Q,
                                                     const float* __restrict__ Kh,
                                                     const int* __restrict__ mask,
                                                     float* __restrict__ S,
                                                     int bh0)
{
    __shared__ __align__(16) float Qs[16][132];
    __shared__ __align__(16) float Ks[16][132];
    const int t  = threadIdx.x;
    const int tx = t & 15, ty = t >> 4;
    const int n0 = blockIdx.x * 128;   // k cols
    const int m0 = blockIdx.y * 128;   // q rows
    const int z  = blockIdx.z;
    const int bh = bh0 + z;
    const int lr = t >> 1;
    const int lk = (t & 1) * 8;

    const float* Qp = &Q [((size_t)bh * SL + m0 + lr) * DHD + lk];
    const float* Kp = &Kh[((size_t)bh * SL + n0 + lr) * DHD + lk];

    float c[8][8] = {};

    for (int k0 = 0; k0 < DHD; k0 += 16) {
        float4 xa0 = *(const float4*)(Qp + k0);
        float4 xa1 = *(const float4*)(Qp + k0 + 4);
        float4 wa0 = *(const float4*)(Kp + k0);
        float4 wa1 = *(const float4*)(Kp + k0 + 4);
        __syncthreads();
        Qs[lk+0][lr]=xa0.x; Qs[lk+1][lr]=xa0.y; Qs[lk+2][lr]=xa0.z; Qs[lk+3][lr]=xa0.w;
        Qs[lk+4][lr]=xa1.x; Qs[lk+5][lr]=xa1.y; Qs[lk+6][lr]=xa1.z; Qs[lk+7][lr]=xa1.w;
        Ks[lk+0][lr]=wa0.x; Ks[lk+1][lr]=wa0.y; Ks[lk+2][lr]=wa0.z; Ks[lk+3][lr]=wa0.w;
        Ks[lk+4][lr]=wa1.x; Ks[lk+5][lr]=wa1.y; Ks[lk+6][lr]=wa1.z; Ks[lk+7][lr]=wa1.w;
        __syncthreads();
        #pragma unroll
        for (int kk = 0; kk < 16; ++kk) {
            float4 a0 = *(const float4*)&Qs[kk][ty * 4];
            float4 a1 = *(const float4*)&Qs[kk][ty * 4 + 64];
            float4 b0 = *(const float4*)&Ks[kk][tx * 4];
            float4 b1 = *(const float4*)&Ks[kk][tx * 4 + 64];
            float a_[8] = {a0.x,a0.y,a0.z,a0.w,a1.x,a1.y,a1.z,a1.w};
            float b_[8] = {b0.x,b0.y,b0.z,b0.w,b1.x,b1.y,b1.z,b1.w};
            #pragma unroll
            for (int i = 0; i < 8; ++i)
                #pragma unroll
                for (int j = 0; j < 8; ++j)
                    c[i][j] = fmaf(a_[i], b_[j], c[i][j]);
        }
    }

    const int b = bh >> 4;
    int4 mk0 = *(const int4*)&mask[(size_t)b * SL + n0 + tx * 4];
    int4 mk1 = *(const int4*)&mask[(size_t)b * SL + n0 + 64 + tx * 4];
    int m_[8] = {mk0.x,mk0.y,mk0.z,mk0.w,mk1.x,mk1.y,mk1.z,mk1.w};
    #pragma unroll
    for (int i = 0; i < 8; ++i) {
        int rr = (i < 4) ? (ty * 4 + i) : (64 + ty * 4 + (i - 4));
        int q  = m0 + rr;
        float r0[4], r1[4];
        #pragma unroll
        for (int j = 0; j < 4; ++j) {
            r0[j] = m_[j]     ? -20000.0f : c[i][j]     * 0.25f;
            r1[j] = m_[j + 4] ? -20000.0f : c[i][j + 4] * 0.25f;
        }
        *(float4*)&S[((size_t)z * SL + q) * SL + n0 + tx * 4] =
            make_float4(r0[0], r0[1], r0[2], r0[3]);
        *(float4*)&S[((size_t)z * SL + q) * SL + n0 + 64 + tx * 4] =
            make_float4(r1[0], r1[1], r1[2], r1[3]);
    }
}

// ---------------------------------------------------------------------------
// Row stats: max, 1/sum(exp), exact top-k threshold (in attn space).
// One row per wave; writes float4 {m, inv, thresh, 0} per row. S unchanged.
// ---------------------------------------------------------------------------
__global__ __launch_bounds__(256) void stats_kernel(const float* __restrict__ S,
                                                    float4* __restrict__ stats)
{
    const int wave = threadIdx.x >> 6;
    const int lane = threadIdx.x & 63;
    const size_t row = (size_t)blockIdx.x * 4 + wave;
    const float4* Sr = (const float4*)(S + row * SL);

    float4 v[8];
    #pragma unroll
    for (int i = 0; i < 8; ++i) v[i] = Sr[lane + 64 * i];

    float m = -1e30f;
    #pragma unroll
    for (int i = 0; i < 8; ++i)
        m = fmaxf(m, fmaxf(fmaxf(v[i].x, v[i].y), fmaxf(v[i].z, v[i].w)));
    #pragma unroll
    for (int o = 32; o > 0; o >>= 1) m = fmaxf(m, __shfl_xor(m, o, 64));

    float sum = 0.0f;
    #pragma unroll
    for (int i = 0; i < 8; ++i) {
        v[i].x = __expf(v[i].x - m); v[i].y = __expf(v[i].y - m);
        v[i].z = __expf(v[i].z - m); v[i].w = __expf(v[i].w - m);
        sum += (v[i].x + v[i].y) + (v[i].z + v[i].w);
    }
    #pragma unroll
    for (int o = 32; o > 0; o >>= 1) sum += __shfl_xor(sum, o, 64);
    float inv = 1.0f / sum;
    #pragma unroll
    for (int i = 0; i < 8; ++i) {
        v[i].x *= inv; v[i].y *= inv; v[i].z *= inv; v[i].w *= inv;
    }

    // binary search on bits: largest thr with count(attn >= thr) >= TOPK
    unsigned lo = 0u, hi = __float_as_uint(inv);   // max attn == inv exactly
    while (lo < hi) {
        unsigned mid = (lo + hi + 1u) >> 1;
        int cnt = 0;
        #pragma unroll
        for (int i = 0; i < 8; ++i) {
            cnt += (__float_as_uint(v[i].x) >= mid);
            cnt += (__float_as_uint(v[i].y) >= mid);
            cnt += (__float_as_uint(v[i].z) >= mid);
            cnt += (__float_as_uint(v[i].w) >= mid);
        }
        #pragma unroll
        for (int o = 32; o > 0; o >>= 1) cnt += __shfl_xor(cnt, o, 64);
        if (cnt >= TOPK) lo = mid; else hi = mid - 1u;
    }

    if (lane == 0)
        stats[row] = make_float4(m, inv, __uint_as_float(lo), 0.0f);
}

// ---------------------------------------------------------------------------
// AV with fused softmax-apply + top-k mask + q-gate.
// CTX[b,q,h*64+d] = (sum_k p(S[z,q,k]) * V[bh,k,d]) * Q[bh,q,d]
// p(s) = mask( exp(s - m)*inv )  -- bitwise identical to stats_kernel's p.
// 128(q) x 64(d) tile, BK=32, 256 threads, 8x4 per thread.
// ---------------------------------------------------------------------------
__global__ __launch_bounds__(256) void av_kernel(const float* __restrict__ S,
                                                 const float4* __restrict__ stats,
                                                 const float* __restrict__ V,
                                                 const float* __restrict__ Q,
                                                 float* __restrict__ CTX,
                                                 int bh0)
{
    __shared__ __align__(16) float Ps[32][132];
    __shared__ __align__(16) float Vs[32][68];
    const int t  = threadIdx.x;
    const int tx = t & 15, ty = t >> 4;
    const int q0 = blockIdx.x * 128;
    const int z  = blockIdx.y;
    const int bh = bh0 + z;
    const int b  = bh >> 4, hh = bh & 15;
    const int lr = t >> 1;          // P staging row 0..127
    const int lc = (t & 1) * 16;    // P staging col base
    const int vr = t >> 3;          // V staging row 0..31
    const int vc = (t & 7) * 8;     // V staging col base

    float4 st = stats[(size_t)z * SL + q0 + lr];
    const float sm   = st.x;
    const float sinv = st.y;
    const unsigned tb = __float_as_uint(st.z);

    const float* Sp = &S[((size_t)z * SL + q0 + lr) * SL + lc];
    const float* Vp = &V[((size_t)bh * SL + vr) * DHD + vc];

    float c[8][4] = {};

    for (int k0 = 0; k0 < SL; k0 += 32) {
        float4 p0 = *(const float4*)(Sp + k0);
        float4 p1 = *(const float4*)(Sp + k0 + 4);
        float4 p2 = *(const float4*)(Sp + k0 + 8);
        float4 p3 = *(const float4*)(Sp + k0 + 12);
        float4 v0 = *(const float4*)(Vp + (size_t)k0 * DHD);
        float4 v1 = *(const float4*)(Vp + (size_t)k0 * DHD + 4);
        __syncthreads();
        float pp[16] = {p0.x,p0.y,p0.z,p0.w, p1.x,p1.y,p1.z,p1.w,
                        p2.x,p2.y,p2.z,p2.w, p3.x,p3.y,p3.z,p3.w};
        #pragma unroll
        for (int u = 0; u < 16; ++u) {
            float e = __expf(pp[u] - sm) * sinv;
            e = (__float_as_uint(e) >= tb) ? e : 0.0f;
            Ps[lc + u][lr] = e;
        }
        *(float4*)&Vs[vr][vc]     = v0;
        *(float4*)&Vs[vr][vc + 4] = v1;
        __syncthreads();
        #pragma unroll
        for (int kk = 0; kk < 32; ++kk) {
            float4 a0 = *(const float4*)&Ps[kk][ty * 4];
            float4 a1 = *(const float4*)&Ps[kk][ty * 4 + 64];
            float4 bv = *(const float4*)&Vs[kk][tx * 4];
            float a_[8] = {a0.x,a0.y,a0.z,a0.w,a1.x,a1.y,a1.z,a1.w};
            float b_[4] = {bv.x,bv.y,bv.z,bv.w};
            #pragma unroll
            for (int i = 0; i < 8; ++i)
                #pragma unroll
                for (int j = 0; j < 4; ++j)
                    c[i][j] = fmaf(a_[i], b_[j], c[i][j]);
        }
    }

    #pragma unroll
    for (int i = 0; i < 8; ++i) {
        int rr = (i < 4) ? (ty * 4 + i) : (64 + ty * 4 + (i - 4));
        int q  = q0 + rr;
        float4 qg = *(const float4*)&Q[((size_t)bh * SL + q) * DHD + tx * 4];
        float4 r = make_float4(c[i][0] * qg.x, c[i][1] * qg.y,
                               c[i][2] * qg.z, c[i][3] * qg.w);
        *(float4*)&CTX[((size_t)b * SL + q) * DM + hh * DHD + tx * 4] = r;
    }
}

// ---------------------------------------------------------------------------
extern "C" void kernel_launch(void* const* d_in, const int* in_sizes, int n_in,
                              void* d_out, int out_size, void* d_ws, size_t ws_size,
                              hipStream_t stream)
{
    const float* q_in = (const float*)d_in[0];
    const float* k_in = (const float*)d_in[1];
    const float* Wq   = (const float*)d_in[2];
    const float* bq   = (const float*)d_in[3];
    const float* Wk   = (const float*)d_in[4];
    const float* bk   = (const float*)d_in[5];
    const float* Wv   = (const float*)d_in[6];
    const float* bv   = (const float*)d_in[7];
    const float* Wo   = (const float*)d_in[8];
    const float* bo   = (const float*)d_in[9];
    const int*   mask = (const int*)d_in[10];   // bool -> int32 per harness
    float* out = (float*)d_out;
    float* ws  = (float*)d_ws;

    float* Qb  = ws + WS_Q;
    float* Kb  = ws + WS_K;
    float* Vb  = ws + WS_V;
    float* CTX = ws + WS_CTX;

    // Adaptive bh-chunking (pure function of ws_size -> graph-capture safe).
    long avail = (long)(ws_size / 4) - (long)WS_S;
    int chunk = 64;
    while (chunk > 1 &&
           (long)chunk * (long)(S_PER_BH + STATS_PER_BH) > avail) chunk >>= 1;

    float*  S     = ws + WS_S;
    float4* stats = (float4*)(ws + WS_S + (size_t)chunk * S_PER_BH);

    dim3 blk(256);
    gemm_proj<<<dim3(8, 64), blk, 0, stream>>>(q_in, Wq, bq, Qb, 0);
    gemm_proj<<<dim3(8, 64), blk, 0, stream>>>(k_in, Wk, bk, Kb, 0);
    gemm_proj<<<dim3(8, 64), blk, 0, stream>>>(k_in, Wv, bv, Vb, 1);

    for (int bh0 = 0; bh0 < NB * NH; bh0 += chunk) {
        scores_kernel<<<dim3(16, 16, chunk), blk, 0, stream>>>(Qb, Kb, mask, S, bh0);
        stats_kernel<<<dim3(chunk * 512), blk, 0, stream>>>(S, stats);
        av_kernel<<<dim3(16, chunk), blk, 0, stream>>>(S, stats, Vb, Qb, CTX, bh0);
    }

    gemm_proj<<<dim3(8, 64), blk, 0, stream>>>(CTX, Wo, bo, out, 2);
}

// Round 5
// 2396.681 us; speedup vs baseline: 2.0891x; 2.0891x over previous
//
#include <hip/hip_runtime.h>
#include <math.h>

// Problem constants
#define NB   4        // batch
#define NH   16       // heads
#define DHD  64       // head dim
#define SL   2048     // Lq == Lk
#define DM   1024     // model dim
#define TOPK 205      // ceil(2048 * 0.1)

// ws layout (floats):
//  Q head-major [B,H,L,DH]  : 8M   @ 0
//  K head-major             : 8M   @ 8M
//  V head-major (tanh)      : 8M   @ 16M
//  CTX [B,L,D]              : 8M   @ 24M
//  S scores/attn [chunk,L,L]: adaptive @ 32M (sized from ws_size)
#define WS_Q   0
#define WS_K   8388608
#define WS_V   16777216
#define WS_CTX 25165824
#define WS_S   33554432
#define S_PER_BH 4194304   // 2048*2048 floats per (b,h) plane

typedef short    bf16x8  __attribute__((ext_vector_type(8)));
typedef float    f32x4   __attribute__((ext_vector_type(4)));
typedef unsigned short ushort8 __attribute__((ext_vector_type(8)));

// Round-to-nearest-even float -> bf16 split: x ~= hi + lo, both bf16.
__device__ inline void split2(float x, unsigned short& h, unsigned short& l)
{
    unsigned u = __float_as_uint(x);
    unsigned r = u + 0x7FFF + ((u >> 16) & 1);
    unsigned short hs = (unsigned short)(r >> 16);
    float hf = __uint_as_float((unsigned)hs << 16);
    float lf = x - hf;
    unsigned ul = __float_as_uint(lf);
    unsigned rl = ul + 0x7FFF + ((ul >> 16) & 1);
    h = hs;
    l = (unsigned short)(rl >> 16);
}

// ---------------------------------------------------------------------------
// Projection GEMM via split-bf16 MFMA: out = X @ W^T + bias.
// X [8192,1024], W [1024,1024] row-major (both k-contiguous -> natural A/B).
// D += Ah*Bh + Ah*Bl + Al*Bh  (ll term dropped; rel err ~2^-17).
// 128x128 block tile, BK=32, 256 threads = 4 waves, each wave 64x64
// (4x4 tiles of 16x16x32 MFMA).  LDS rows padded to 40 bf16 (2-way banks).
// mode 0: head-major write; 1: +tanh; 2: plain [M,N].
// ---------------------------------------------------------------------------
__global__ __launch_bounds__(256) void gemm_proj_mfma(const float* __restrict__ X,
                                                      const float* __restrict__ W,
                                                      const float* __restrict__ bias,
                                                      float* __restrict__ out,
                                                      int mode)
{
    __shared__ unsigned short Ah[128 * 40];
    __shared__ unsigned short Al[128 * 40];
    __shared__ unsigned short Bh[128 * 40];
    __shared__ unsigned short Bl[128 * 40];

    const int t    = threadIdx.x;
    const int lane = t & 63;
    const int wv   = t >> 6;
    const int wm   = (wv & 1) * 64;
    const int wn   = (wv >> 1) * 64;
    const int n0   = blockIdx.x * 128;
    const int m0   = blockIdx.y * 128;
    const int ra   = t >> 1;          // staging row 0..127
    const int ca   = (t & 1) * 16;    // staging col base 0/16

    const float* Xp = X + (size_t)(m0 + ra) * DM + ca;
    const float* Wp = W + (size_t)(n0 + ra) * DM + ca;

    f32x4 acc[4][4] = {};

    const int lm   = lane & 15;       // fragment row/col within 16
    const int koff = (lane >> 4) * 8; // k offset within BK=32

    for (int kb = 0; kb < DM; kb += 32) {
        // ---- global load 16 floats per side per thread ----
        float4 xv[4], wvv[4];
        #pragma unroll
        for (int q = 0; q < 4; ++q) {
            xv[q]  = *(const float4*)(Xp + kb + q * 4);
            wvv[q] = *(const float4*)(Wp + kb + q * 4);
        }
        __syncthreads();   // previous iteration's readers done
        // ---- convert + stage ----
        ushort8 xh[2], xl[2], wh[2], wl[2];
        #pragma unroll
        for (int g = 0; g < 2; ++g)
            #pragma unroll
            for (int e = 0; e < 8; ++e) {
                unsigned short h_, l_;
                split2(((const float*)xv)[g * 8 + e], h_, l_);
                xh[g][e] = h_; xl[g][e] = l_;
                split2(((const float*)wvv)[g * 8 + e], h_, l_);
                wh[g][e] = h_; wl[g][e] = l_;
            }
        *(ushort8*)&Ah[ra * 40 + ca]     = xh[0];
        *(ushort8*)&Ah[ra * 40 + ca + 8] = xh[1];
        *(ushort8*)&Al[ra * 40 + ca]     = xl[0];
        *(ushort8*)&Al[ra * 40 + ca + 8] = xl[1];
        *(ushort8*)&Bh[ra * 40 + ca]     = wh[0];
        *(ushort8*)&Bh[ra * 40 + ca + 8] = wh[1];
        *(ushort8*)&Bl[ra * 40 + ca]     = wl[0];
        *(ushort8*)&Bl[ra * 40 + ca + 8] = wl[1];
        __syncthreads();
        // ---- fragments + MFMA ----
        bf16x8 a_h[4], a_l[4], b_h[4], b_l[4];
        #pragma unroll
        for (int i = 0; i < 4; ++i) {
            int idx = (wm + i * 16 + lm) * 40 + koff;
            a_h[i] = *(const bf16x8*)&Ah[idx];
            a_l[i] = *(const bf16x8*)&Al[idx];
        }
        #pragma unroll
        for (int j = 0; j < 4; ++j) {
            int jdx = (wn + j * 16 + lm) * 40 + koff;
            b_h[j] = *(const bf16x8*)&Bh[jdx];
            b_l[j] = *(const bf16x8*)&Bl[jdx];
        }
        #pragma unroll
        for (int i = 0; i < 4; ++i)
            #pragma unroll
            for (int j = 0; j < 4; ++j) {
                acc[i][j] = __builtin_amdgcn_mfma_f32_16x16x32_bf16(
                    a_h[i], b_h[j], acc[i][j], 0, 0, 0);
                acc[i][j] = __builtin_amdgcn_mfma_f32_16x16x32_bf16(
                    a_h[i], b_l[j], acc[i][j], 0, 0, 0);
                acc[i][j] = __builtin_amdgcn_mfma_f32_16x16x32_bf16(
                    a_l[i], b_h[j], acc[i][j], 0, 0, 0);
            }
    }

    // ---- epilogue: C/D layout col=lane&15 (n), row=(lane>>4)*4+r (m) ----
    const int rq = (lane >> 4) * 4;
    #pragma unroll
    for (int j = 0; j < 4; ++j) {
        int n = n0 + wn + j * 16 + lm;
        float bb = bias[n];
        #pragma unroll
        for (int i = 0; i < 4; ++i) {
            #pragma unroll
            for (int r = 0; r < 4; ++r) {
                int m = m0 + wm + i * 16 + rq + r;
                float v = acc[i][j][r] + bb;
                if (mode == 1) v = tanhf(v);
                if (mode == 2) {
                    out[(size_t)m * DM + n] = v;
                } else {
                    int b = m >> 11, l = m & 2047, hh = n >> 6, d = n & 63;
                    out[(((size_t)(b * NH + hh)) * SL + l) * DHD + d] = v;
                }
            }
        }
    }
}

// ---------------------------------------------------------------------------
// Scores: S[z,q,k] = 0.25 * sum_d Q[bh,q,d]*K[bh,k,d]; masked -> -20000
// (round-3 measured version) grid (32,32,chunk), 64x64 tile, BK=64.
// ---------------------------------------------------------------------------
__global__ __launch_bounds__(256) void scores_kernel(const float* __restrict__ Q,
                                                     const float* __restrict__ Kh,
                                                     const int* __restrict__ mask,
                                                     float* __restrict__ S,
                                                     int bh0)
{
    __shared__ __align__(16) float Qs[64][68];   // [d][q]
    __shared__ __align__(16) float Ks[64][68];   // [d][k]
    const int t  = threadIdx.x;
    const int tx = t & 15, ty = t >> 4;
    const int k0 = blockIdx.x * 64;
    const int q0 = blockIdx.y * 64;
    const int z  = blockIdx.z;
    const int bh = bh0 + z;
    const float* Qbase = Q + ((size_t)bh * SL + q0) * DHD;
    const float* Kbase = Kh + ((size_t)bh * SL + k0) * DHD;

    #pragma unroll
    for (int i = 0; i < 4; ++i) {
        int e = t + 256 * i;
        int row = e >> 4;
        int dq  = (e & 15) * 4;
        float4 qa = *(const float4*)&Qbase[row * DHD + dq];
        float4 ka = *(const float4*)&Kbase[row * DHD + dq];
        Qs[dq + 0][row] = qa.x; Qs[dq + 1][row] = qa.y;
        Qs[dq + 2][row] = qa.z; Qs[dq + 3][row] = qa.w;
        Ks[dq + 0][row] = ka.x; Ks[dq + 1][row] = ka.y;
        Ks[dq + 2][row] = ka.z; Ks[dq + 3][row] = ka.w;
    }
    __syncthreads();

    float c[4][4] = {};
    #pragma unroll 8
    for (int d = 0; d < 64; ++d) {
        float4 a4 = *(const float4*)&Qs[d][ty * 4];
        float4 b4 = *(const float4*)&Ks[d][tx * 4];
        float a_[4] = {a4.x, a4.y, a4.z, a4.w};
        float b_[4] = {b4.x, b4.y, b4.z, b4.w};
        #pragma unroll
        for (int i = 0; i < 4; ++i)
            #pragma unroll
            for (int j = 0; j < 4; ++j)
                c[i][j] = fmaf(a_[i], b_[j], c[i][j]);
    }

    const int b = bh >> 4;
    int4 mk = *(const int4*)&mask[(size_t)b * SL + k0 + tx * 4];
    int m_[4] = {mk.x, mk.y, mk.z, mk.w};
    #pragma unroll
    for (int i = 0; i < 4; ++i) {
        int q = q0 + ty * 4 + i;
        float r_[4];
        #pragma unroll
        for (int j = 0; j < 4; ++j)
            r_[j] = m_[j] ? -20000.0f : c[i][j] * 0.25f;
        *(float4*)&S[((size_t)z * SL + q) * SL + k0 + tx * 4] =
            make_float4(r_[0], r_[1], r_[2], r_[3]);
    }
}

// ---------------------------------------------------------------------------
// Softmax + exact top-k threshold mask, in place on S (round-3 version).
// One row per wave; row cached in 32 VGPRs; bitwise binary search.
// ---------------------------------------------------------------------------
__global__ __launch_bounds__(256) void softmax_topk(float* __restrict__ S)
{
    const int wave = threadIdx.x >> 6;
    const int lane = threadIdx.x & 63;
    const size_t row = (size_t)blockIdx.x * 4 + wave;
    float4* Sr = (float4*)(S + row * SL);               // 512 float4

    float4 v[8];
    #pragma unroll
    for (int i = 0; i < 8; ++i) v[i] = Sr[lane + 64 * i];

    float m = -1e30f;
    #pragma unroll
    for (int i = 0; i < 8; ++i)
        m = fmaxf(m, fmaxf(fmaxf(v[i].x, v[i].y), fmaxf(v[i].z, v[i].w)));
    #pragma unroll
    for (int o = 32; o > 0; o >>= 1) m = fmaxf(m, __shfl_xor(m, o, 64));

    float sum = 0.0f;
    #pragma unroll
    for (int i = 0; i < 8; ++i) {
        v[i].x = __expf(v[i].x - m); v[i].y = __expf(v[i].y - m);
        v[i].z = __expf(v[i].z - m); v[i].w = __expf(v[i].w - m);
        sum += (v[i].x + v[i].y) + (v[i].z + v[i].w);
    }
    #pragma unroll
    for (int o = 32; o > 0; o >>= 1) sum += __shfl_xor(sum, o, 64);
    float inv = 1.0f / sum;
    #pragma unroll
    for (int i = 0; i < 8; ++i) {
        v[i].x *= inv; v[i].y *= inv; v[i].z *= inv; v[i].w *= inv;
    }

    unsigned lo = 0u, hi = __float_as_uint(inv);
    while (lo < hi) {
        unsigned mid = (lo + hi + 1u) >> 1;
        int cnt = 0;
        #pragma unroll
        for (int i = 0; i < 8; ++i) {
            cnt += (__float_as_uint(v[i].x) >= mid);
            cnt += (__float_as_uint(v[i].y) >= mid);
            cnt += (__float_as_uint(v[i].z) >= mid);
            cnt += (__float_as_uint(v[i].w) >= mid);
        }
        #pragma unroll
        for (int o = 32; o > 0; o >>= 1) cnt += __shfl_xor(cnt, o, 64);
        if (cnt >= TOPK) lo = mid; else hi = mid - 1u;
    }

    #pragma unroll
    for (int i = 0; i < 8; ++i) {
        float4 x = v[i];
        x.x = (__float_as_uint(x.x) >= lo) ? x.x : 0.0f;
        x.y = (__float_as_uint(x.y) >= lo) ? x.y : 0.0f;
        x.z = (__float_as_uint(x.z) >= lo) ? x.z : 0.0f;
        x.w = (__float_as_uint(x.w) >= lo) ? x.w : 0.0f;
        Sr[lane + 64 * i] = x;
    }
}

// ---------------------------------------------------------------------------
// CTX[b, q, h*64+d] = (sum_k attn[z,q,k] * V[bh,k,d]) * Q[bh,q,d]
// (round-3 measured version) grid (32,chunk), 64x64 tile.
// ---------------------------------------------------------------------------
__global__ __launch_bounds__(256) void av_kernel(const float* __restrict__ S,
                                                 const float* __restrict__ V,
                                                 const float* __restrict__ Q,
                                                 float* __restrict__ CTX,
                                                 int bh0)
{
    __shared__ __align__(16) float As[64][68];   // [k][q]
    __shared__ __align__(16) float Vs[64][68];   // [k][d]
    const int t  = threadIdx.x;
    const int tx = t & 15, ty = t >> 4;
    const int q0 = blockIdx.x * 64;
    const int z  = blockIdx.y;
    const int bh = bh0 + z;
    const int b  = bh >> 4, hh = bh & 15;

    float c[4][4] = {};

    for (int k0 = 0; k0 < SL; k0 += 64) {
        float4 av[4], vv[4];
        #pragma unroll
        for (int i = 0; i < 4; ++i) {
            int e = t + 256 * i;
            int row = e >> 4;
            int kq  = (e & 15) * 4;
            av[i] = *(const float4*)&S[((size_t)z * SL + q0 + row) * SL + k0 + kq];
            vv[i] = *(const float4*)&V[((size_t)bh * SL + k0 + row) * DHD + kq];
        }
        __syncthreads();
        #pragma unroll
        for (int i = 0; i < 4; ++i) {
            int e = t + 256 * i;
            int row = e >> 4;
            int kq  = (e & 15) * 4;
            As[kq + 0][row] = av[i].x; As[kq + 1][row] = av[i].y;
            As[kq + 2][row] = av[i].z; As[kq + 3][row] = av[i].w;
            *(float4*)&Vs[row][kq] = vv[i];
        }
        __syncthreads();
        #pragma unroll 8
        for (int kk = 0; kk < 64; ++kk) {
            float4 a4 = *(const float4*)&As[kk][ty * 4];
            float4 b4 = *(const float4*)&Vs[kk][tx * 4];
            float a_[4] = {a4.x, a4.y, a4.z, a4.w};
            float b_[4] = {b4.x, b4.y, b4.z, b4.w};
            #pragma unroll
            for (int i = 0; i < 4; ++i)
                #pragma unroll
                for (int j = 0; j < 4; ++j)
                    c[i][j] = fmaf(a_[i], b_[j], c[i][j]);
        }
        __syncthreads();
    }

    #pragma unroll
    for (int i = 0; i < 4; ++i) {
        int q = q0 + ty * 4 + i;
        float4 qg = *(const float4*)&Q[((size_t)bh * SL + q) * DHD + tx * 4];
        float4 r = make_float4(c[i][0] * qg.x, c[i][1] * qg.y,
                               c[i][2] * qg.z, c[i][3] * qg.w);
        *(float4*)&CTX[((size_t)b * SL + q) * DM + hh * DHD + tx * 4] = r;
    }
}

// ---------------------------------------------------------------------------
extern "C" void kernel_launch(void* const* d_in, const int* in_sizes, int n_in,
                              void* d_out, int out_size, void* d_ws, size_t ws_size,
                              hipStream_t stream)
{
    const float* q_in = (const float*)d_in[0];
    const float* k_in = (const float*)d_in[1];
    const float* Wq   = (const float*)d_in[2];
    const float* bq   = (const float*)d_in[3];
    const float* Wk   = (const float*)d_in[4];
    const float* bk   = (const float*)d_in[5];
    const float* Wv   = (const float*)d_in[6];
    const float* bv   = (const float*)d_in[7];
    const float* Wo   = (const float*)d_in[8];
    const float* bo   = (const float*)d_in[9];
    const int*   mask = (const int*)d_in[10];   // bool -> int32 per harness
    float* out = (float*)d_out;
    float* ws  = (float*)d_ws;

    float* Qb  = ws + WS_Q;
    float* Kb  = ws + WS_K;
    float* Vb  = ws + WS_V;
    float* CTX = ws + WS_CTX;
    float* S   = ws + WS_S;

    // Adaptive bh-chunking (pure function of ws_size -> graph-capture safe).
    long s_cap_floats = (long)(ws_size / 4) - (long)WS_S;
    int chunk = 64;
    while (chunk > 1 && (long)chunk * (long)S_PER_BH > s_cap_floats) chunk >>= 1;

    dim3 blk(256);
    gemm_proj_mfma<<<dim3(8, 64), blk, 0, stream>>>(q_in, Wq, bq, Qb, 0);
    gemm_proj_mfma<<<dim3(8, 64), blk, 0, stream>>>(k_in, Wk, bk, Kb, 0);
    gemm_proj_mfma<<<dim3(8, 64), blk, 0, stream>>>(k_in, Wv, bv, Vb, 1);

    for (int bh0 = 0; bh0 < NB * NH; bh0 += chunk) {
        scores_kernel<<<dim3(32, 32, chunk), blk, 0, stream>>>(Qb, Kb, mask, S, bh0);
        softmax_topk<<<dim3(chunk * 512), blk, 0, stream>>>(S);
        av_kernel<<<dim3(32, chunk), blk, 0, stream>>>(S, Vb, Qb, CTX, bh0);
    }

    gemm_proj_mfma<<<dim3(8, 64), blk, 0, stream>>>(CTX, Wo, bo, out, 2);
}